// Round 1
// 2099.497 us; speedup vs baseline: 6.8049x; 6.8049x over previous
//
#include <hip/hip_runtime.h>
#include <hip/hip_bf16.h>

#define NN 40000      // nodes
#define NE 150000     // edges per type
#define HF 512        // H*D
#define NHEAD 4

typedef __bf16 bf16x8 __attribute__((ext_vector_type(8)));
typedef float floatx4 __attribute__((ext_vector_type(4)));
typedef __hip_bfloat16 bf16;
typedef unsigned short u16;

__device__ __forceinline__ float bf2f(bf16 v) { return __bfloat162float(v); }

// ---------------- cast fp32 -> bf16, elementwise ----------------
__global__ void cast_k(const float* __restrict__ in, bf16* __restrict__ out, int n) {
    int i = (blockIdx.x * blockDim.x + threadIdx.x) * 4;
    if (i + 3 < n) {
        float4 v = *(const float4*)(in + i);
        out[i + 0] = __float2bfloat16(v.x);
        out[i + 1] = __float2bfloat16(v.y);
        out[i + 2] = __float2bfloat16(v.z);
        out[i + 3] = __float2bfloat16(v.w);
    } else {
        for (int j = i; j < n; j++) out[j] = __float2bfloat16(in[j]);
    }
}

// ---------------- transpose+cast: WT[n*K+k] = bf16(W[k*N+n]) ----------------
__global__ void transpose_k(const float* __restrict__ W, bf16* __restrict__ WT,
                            int K, int Nn) {
    __shared__ float tile[32][33];
    int n0 = blockIdx.x * 32, k0 = blockIdx.y * 32;
    int tx = threadIdx.x, ty = threadIdx.y;
    int n = n0 + tx, k = k0 + ty;
    if (n < Nn && k < K) tile[ty][tx] = W[(size_t)k * Nn + n];
    __syncthreads();
    int nn = n0 + ty, kk = k0 + tx;
    if (nn < Nn && kk < K) WT[(size_t)nn * K + kk] = __float2bfloat16(tile[tx][ty]);
}

// ---------------- GEMM: C[M,Nn] = A[M,K] * BT[Nn,K]^T ----------------
template <bool HAS_BIAS>
__global__ __launch_bounds__(256) void gemm_k(const bf16* __restrict__ A,
                                              const bf16* __restrict__ BT,
                                              float* __restrict__ C,
                                              const float* __restrict__ bias,
                                              int M, int Nn, int K) {
    __shared__ __align__(16) unsigned short As[64][40];
    __shared__ __align__(16) unsigned short Bs[64][40];
    const int m0 = blockIdx.x * 64;
    const int n0 = blockIdx.y * 64;
    const int t = threadIdx.x;
    const int lane = t & 63;
    const int wave = t >> 6;
    const int wm = wave >> 1, wn = wave & 1;
    const int q = lane >> 4, r = lane & 15;
    const int srow = t >> 2;
    const int scol = (t & 3) * 8;
    const bool a_ok = (m0 + srow) < M;
    const bool b_ok = (n0 + srow) < Nn;
    const unsigned short* Arow = (const unsigned short*)A + (size_t)(m0 + srow) * K + scol;
    const unsigned short* Brow = (const unsigned short*)BT + (size_t)(n0 + srow) * K + scol;

    floatx4 acc[2][2] = {};
    for (int k0 = 0; k0 < K; k0 += 32) {
        uint4 av = make_uint4(0, 0, 0, 0), bv = make_uint4(0, 0, 0, 0);
        if (a_ok) av = *(const uint4*)(Arow + k0);
        if (b_ok) bv = *(const uint4*)(Brow + k0);
        *(uint4*)&As[srow][scol] = av;
        *(uint4*)&Bs[srow][scol] = bv;
        __syncthreads();
        bf16x8 a0 = *(const bf16x8*)&As[wm * 32 + r][q * 8];
        bf16x8 a1 = *(const bf16x8*)&As[wm * 32 + 16 + r][q * 8];
        bf16x8 b0 = *(const bf16x8*)&Bs[wn * 32 + r][q * 8];
        bf16x8 b1 = *(const bf16x8*)&Bs[wn * 32 + 16 + r][q * 8];
        acc[0][0] = __builtin_amdgcn_mfma_f32_16x16x32_bf16(a0, b0, acc[0][0], 0, 0, 0);
        acc[0][1] = __builtin_amdgcn_mfma_f32_16x16x32_bf16(a0, b1, acc[0][1], 0, 0, 0);
        acc[1][0] = __builtin_amdgcn_mfma_f32_16x16x32_bf16(a1, b0, acc[1][0], 0, 0, 0);
        acc[1][1] = __builtin_amdgcn_mfma_f32_16x16x32_bf16(a1, b1, acc[1][1], 0, 0, 0);
        __syncthreads();
    }
#pragma unroll
    for (int i = 0; i < 2; i++)
#pragma unroll
        for (int j = 0; j < 2; j++)
#pragma unroll
            for (int rr = 0; rr < 4; rr++) {
                int row = m0 + wm * 32 + i * 16 + q * 4 + rr;
                int col = n0 + wn * 32 + j * 16 + r;
                if (row < M && col < Nn) {
                    float v = acc[i][j][rr];
                    if (HAS_BIAS) v += bias[col];
                    C[(size_t)row * Nn + col] = v;
                }
            }
}

// ---------------- attention logits: el/er[n,h] = <feat[n,h,:], al/ar[h,:]> ----
__global__ void attn_k(const float* __restrict__ feat, const float* __restrict__ al,
                       const float* __restrict__ ar, float* __restrict__ el,
                       float* __restrict__ er) {
    int lane = threadIdx.x & 63;
    int wave = threadIdx.x >> 6;
    int node = blockIdx.x * 4 + wave;
    if (node >= NN) return;
    int h = lane >> 4;
    const float* fp = feat + (size_t)node * HF + lane * 8;
    float4 f0 = *(const float4*)fp;
    float4 f1 = *(const float4*)(fp + 4);
    const float* alp = al + h * 128 + (lane & 15) * 8;
    const float* arp = ar + h * 128 + (lane & 15) * 8;
    float fv[8] = {f0.x, f0.y, f0.z, f0.w, f1.x, f1.y, f1.z, f1.w};
    float sl = 0.f, sr = 0.f;
#pragma unroll
    for (int j = 0; j < 8; j++) {
        sl += fv[j] * alp[j];
        sr += fv[j] * arp[j];
    }
#pragma unroll
    for (int off = 8; off >= 1; off >>= 1) {
        sl += __shfl_down(sl, off, 16);
        sr += __shfl_down(sr, off, 16);
    }
    if ((lane & 15) == 0) {
        el[node * NHEAD + h] = sl;
        er[node * NHEAD + h] = sr;
    }
}

// ---------------- CSR build: degree histogram ----------------
__global__ void deg_count_k(const int* __restrict__ dst, int* __restrict__ deg) {
    int e = blockIdx.x * blockDim.x + threadIdx.x;
    if (e < NE) atomicAdd(&deg[dst[e]], 1);
}

// ---------------- CSR build: exclusive scan (single block, 1024 thr) --------
__global__ void scan_k(const int* __restrict__ deg, int* __restrict__ off) {
    __shared__ int part[1024];
    const int CH = (NN + 1023) >> 10;  // elements per thread
    int t = threadIdx.x;
    int base = t * CH;
    int s = 0;
    for (int i = 0; i < CH; i++) {
        int idx = base + i;
        if (idx < NN) s += deg[idx];
    }
    part[t] = s;
    __syncthreads();
    // Hillis-Steele inclusive scan over partial sums
    for (int d = 1; d < 1024; d <<= 1) {
        int v = (t >= d) ? part[t - d] : 0;
        __syncthreads();
        part[t] += v;
        __syncthreads();
    }
    int run = (t == 0) ? 0 : part[t - 1];
    for (int i = 0; i < CH; i++) {
        int idx = base + i;
        if (idx < NN) {
            off[idx] = run;
            run += deg[idx];
        } else if (idx == NN) {
            off[NN] = run;
        }
    }
}

// ---------------- CSR build: fill sorted src list ----------------
__global__ void fill_k(const int* __restrict__ src, const int* __restrict__ dst,
                       const int* __restrict__ off, int* __restrict__ cur,
                       int* __restrict__ csrc) {
    int e = blockIdx.x * blockDim.x + threadIdx.x;
    if (e >= NE) return;
    int d = dst[e];
    int p = atomicAdd(&cur[d], 1);
    csrc[off[d] + p] = src[e];
}

// ---------------- fused: edge softmax + gather + bias + act + type-sum ------
// One wave per dst node. Lane owns 8 contiguous floats of the 512-wide row;
// head h = lane>>4. 3 passes over the in-edge list: max, exp-sum, weighted
// accumulate (registers only, no atomics).
__global__ __launch_bounds__(256) void gather_k(
    const int* __restrict__ off, const int* __restrict__ csrc,
    const float* __restrict__ el, const float* __restrict__ er,
    const float* __restrict__ feat, const float* __restrict__ bt,
    bf16* __restrict__ hout, int first, int act) {
    int lane = threadIdx.x & 63;
    int wave = threadIdx.x >> 6;
    int d = blockIdx.x * 4 + wave;
    if (d >= NN) return;
    int h = lane >> 4;
    int o0 = off[d], o1 = off[d + 1];
    float erd = er[d * NHEAD + h];

    // pass 1: segment max of leaky(el[s]+er[d])
    float m = -3.0e38f;
    for (int i = o0; i < o1; i++) {
        int s = csrc[i];
        float lg = el[s * NHEAD + h] + erd;
        lg = lg > 0.f ? lg : 0.2f * lg;
        m = fmaxf(m, lg);
    }
    // pass 2: exp-sum
    float sum = 0.f;
    for (int i = o0; i < o1; i++) {
        int s = csrc[i];
        float lg = el[s * NHEAD + h] + erd;
        lg = lg > 0.f ? lg : 0.2f * lg;
        sum += __expf(lg - m);
    }
    float inv = sum > 0.f ? 1.f / sum : 0.f;
    // pass 3: weighted gather into registers
    float acc[8] = {};
    for (int i = o0; i < o1; i++) {
        int s = csrc[i];
        float lg = el[s * NHEAD + h] + erd;
        lg = lg > 0.f ? lg : 0.2f * lg;
        float a = __expf(lg - m) * inv;
        const float* fp = feat + (size_t)s * HF + lane * 8;
        float4 f0 = *(const float4*)fp;
        float4 f1 = *(const float4*)(fp + 4);
        acc[0] += f0.x * a;
        acc[1] += f0.y * a;
        acc[2] += f0.z * a;
        acc[3] += f0.w * a;
        acc[4] += f1.x * a;
        acc[5] += f1.y * a;
        acc[6] += f1.z * a;
        acc[7] += f1.w * a;
    }
    // epilogue: + bias, activation, sum over edge types into bf16 hout
    const float* bp = bt + lane * 8;
    float4 b0 = *(const float4*)bp;
    float4 b1 = *(const float4*)(bp + 4);
    float bv[8] = {b0.x, b0.y, b0.z, b0.w, b1.x, b1.y, b1.z, b1.w};
    u16* hp = (u16*)(hout + (size_t)d * HF + lane * 8);
    union U8 { uint4 v; u16 s[8]; };
    U8 prev;
    if (!first) prev.v = *(const uint4*)hp;
    U8 outw;
#pragma unroll
    for (int j = 0; j < 8; j++) {
        float v = acc[j] + bv[j];
        if (act) v = v > 0.f ? v : 0.01f * v;
        if (!first) {
            bf16 pb = *(const bf16*)&prev.s[j];
            v += bf2f(pb);
        }
        bf16 ob = __float2bfloat16(v);
        outw.s[j] = *(const u16*)&ob;
    }
    *(uint4*)hp = outw.v;
}

extern "C" void kernel_launch(void* const* d_in, const int* in_sizes, int n_in,
                              void* d_out, int out_size, void* d_ws, size_t ws_size,
                              hipStream_t stream) {
    const float* x = (const float*)d_in[0];
    const int* srcs[2] = {(const int*)d_in[1], (const int*)d_in[3]};
    const int* dsts[2] = {(const int*)d_in[2], (const int*)d_in[4]};
    const float* W[3] = {(const float*)d_in[5], (const float*)d_in[9], (const float*)d_in[13]};
    const float* al[3] = {(const float*)d_in[6], (const float*)d_in[10], (const float*)d_in[14]};
    const float* ar[3] = {(const float*)d_in[7], (const float*)d_in[11], (const float*)d_in[15]};
    const float* bb[3] = {(const float*)d_in[8], (const float*)d_in[12], (const float*)d_in[16]};
    const float* Wout = (const float*)d_in[17];
    const float* bout = (const float*)d_in[18];

    // workspace layout (~170 MB)
    char* ws = (char*)d_ws;
    size_t off = 0;
    auto walloc = [&](size_t bytes) {
        void* p = ws + off;
        off = (off + bytes + 255) & ~(size_t)255;
        return p;
    };
    bf16* h0 = (bf16*)walloc((size_t)NN * HF * 2);
    bf16* h1 = (bf16*)walloc((size_t)NN * HF * 2);
    float* feat = (float*)walloc((size_t)NN * HF * 4);
    float* el = (float*)walloc((size_t)NN * NHEAD * 4);
    float* er = (float*)walloc((size_t)NN * NHEAD * 4);
    bf16* WT = (bf16*)walloc((size_t)2983 * 512 * 2);
    int* deg = (int*)walloc((size_t)NN * 4);
    int* cur = (int*)walloc((size_t)NN * 4);
    int* offs[2];
    int* csrc[2];
    for (int t = 0; t < 2; t++) {
        offs[t] = (int*)walloc((size_t)(NN + 1) * 4);
        csrc[t] = (int*)walloc((size_t)NE * 4);
    }

    // dead region of d_out used as scratch for bf16 x (out is fp32, 477 MB;
    // final GEMM overwrites everything).
    bf16* xb = (bf16*)((char*)d_out + (size_t)NN * HF * 4);

    // cast x (fp32 -> bf16) once
    cast_k<<<(NN * 1024 / 4 + 255) / 256, 256, 0, stream>>>(x, xb, NN * 1024);

    // build dst-CSR per edge type (reused across all 3 layers)
    const int EB = (NE + 255) / 256;
    for (int t = 0; t < 2; t++) {
        hipMemsetAsync(deg, 0, (size_t)NN * 4, stream);
        hipMemsetAsync(cur, 0, (size_t)NN * 4, stream);
        deg_count_k<<<EB, 256, 0, stream>>>(dsts[t], deg);
        scan_k<<<1, 1024, 0, stream>>>(deg, offs[t]);
        fill_k<<<EB, 256, 0, stream>>>(srcs[t], dsts[t], offs[t], cur, csrc[t]);
    }

    for (int l = 0; l < 3; l++) {
        const int K = (l == 0) ? 1024 : 512;
        const bf16* hin = (l == 0) ? xb : ((l == 1) ? h0 : h1);
        bf16* hout = (l == 0) ? h0 : ((l == 1) ? h1 : h0);
        const int act = (l < 2) ? 1 : 0;
        for (int t = 0; t < 2; t++) {
            // feat = hin @ W[l][t]
            transpose_k<<<dim3(512 / 32, K / 32), dim3(32, 32), 0, stream>>>(
                W[l] + (size_t)t * K * 512, WT, K, 512);
            gemm_k<false><<<dim3(NN / 64, 512 / 64), 256, 0, stream>>>(
                hin, WT, feat, nullptr, NN, 512, K);
            // logits
            attn_k<<<NN / 4, 256, 0, stream>>>(feat, al[l] + t * HF, ar[l] + t * HF, el, er);
            // fused edge-softmax + aggregate + bias + activation + type-sum
            gather_k<<<NN / 4, 256, 0, stream>>>(offs[t], csrc[t], el, er, feat,
                                                 bb[l] + t * HF, hout, t == 0 ? 1 : 0, act);
        }
    }

    // final projection: out = h @ Wout + bout   [40000 x 2983] fp32
    transpose_k<<<dim3((2983 + 31) / 32, 512 / 32), dim3(32, 32), 0, stream>>>(
        Wout, WT, 512, 2983);
    gemm_k<true><<<dim3(NN / 64, (2983 + 63) / 64), 256, 0, stream>>>(
        h0, WT, (float*)d_out, bout, NN, 2983, 512);
}

// Round 2
// 1811.207 us; speedup vs baseline: 7.8881x; 1.1592x over previous
//
#include <hip/hip_runtime.h>
#include <hip/hip_bf16.h>

#define NN 40000      // nodes
#define NE 150000     // edges per type
#define HF 512        // H*D
#define NHEAD 4

typedef __bf16 bf16x8 __attribute__((ext_vector_type(8)));
typedef float floatx4 __attribute__((ext_vector_type(4)));
typedef __hip_bfloat16 bf16;
typedef unsigned short u16;

__device__ __forceinline__ float bf2f(bf16 v) { return __bfloat162float(v); }

// ---------------- cast fp32 -> bf16, elementwise (8/thread, 16B stores) -----
__global__ void cast_k(const float* __restrict__ in, bf16* __restrict__ out, int n) {
    int i = (blockIdx.x * blockDim.x + threadIdx.x) * 8;
    if (i + 7 < n) {
        float4 v0 = *(const float4*)(in + i);
        float4 v1 = *(const float4*)(in + i + 4);
        union { uint4 u; u16 s[8]; } w;
        float fv[8] = {v0.x, v0.y, v0.z, v0.w, v1.x, v1.y, v1.z, v1.w};
#pragma unroll
        for (int j = 0; j < 8; j++) {
            bf16 b = __float2bfloat16(fv[j]);
            w.s[j] = *(const u16*)&b;
        }
        *(uint4*)(out + i) = w.u;
    } else {
        for (int j = i; j < n; j++) out[j] = __float2bfloat16(in[j]);
    }
}

// ---------------- transpose+cast: WT[n*K+k] = bf16(W[k*N+n]) ----------------
__global__ void transpose_k(const float* __restrict__ W, bf16* __restrict__ WT,
                            int K, int Nn) {
    __shared__ float tile[32][33];
    int n0 = blockIdx.x * 32, k0 = blockIdx.y * 32;
    int tx = threadIdx.x, ty = threadIdx.y;
    int n = n0 + tx, k = k0 + ty;
    if (n < Nn && k < K) tile[ty][tx] = W[(size_t)k * Nn + n];
    __syncthreads();
    int nn = n0 + ty, kk = k0 + tx;
    if (nn < Nn && kk < K) WT[(size_t)nn * K + kk] = __float2bfloat16(tile[tx][ty]);
}

// ---------------- GEMM: C[M,Nn] = A[M,K] * BT[Nn,K]^T ----------------
// 128x128 tile, 4 waves (2x2), each wave 64x64 = 4x4 frags of 16x16x32 bf16.
// grid: (ntiles, mtiles) — blockIdx.x walks N so consecutive blocks share the
// A row-panel; bijective XCD swizzle keeps panel-sharers on one XCD L2.
template <bool HAS_BIAS>
__global__ __launch_bounds__(256) void gemm_k(const bf16* __restrict__ A,
                                              const bf16* __restrict__ BT,
                                              float* __restrict__ C,
                                              const float* __restrict__ bias,
                                              int M, int Nn, int K) {
    __shared__ __align__(16) unsigned short As[128][40];
    __shared__ __align__(16) unsigned short Bs[128][40];

    // bijective XCD swizzle (m204 form; nwg % 8 may be nonzero)
    const int nwg = gridDim.x * gridDim.y;
    const int orig = blockIdx.y * gridDim.x + blockIdx.x;
    const int qq = nwg >> 3, r8 = nwg & 7;
    const int xcd = orig & 7, loc = orig >> 3;
    const int swz = (xcd < r8 ? xcd * (qq + 1) : r8 * (qq + 1) + (xcd - r8) * qq) + loc;
    const int ntile = swz % gridDim.x;
    const int mtile = swz / gridDim.x;
    const int m0 = mtile * 128;
    const int n0 = ntile * 128;

    const int t = threadIdx.x;
    const int lane = t & 63;
    const int wave = t >> 6;
    const int wm = wave >> 1, wn = wave & 1;
    const int q = lane >> 4, r = lane & 15;

    // staging: thread t loads 32B of row (t>>1), halves by (t&1)
    const int srow = t >> 1;
    const int scol = (t & 1) << 4;
    const int arow = m0 + srow;
    const int brow = n0 + srow;
    const bool a_ok = arow < M;
    const bool b_ok = brow < Nn;
    const unsigned short* Arow = (const unsigned short*)A + (size_t)arow * K + scol;
    const unsigned short* Brow = (const unsigned short*)BT + (size_t)brow * K + scol;

    floatx4 acc[4][4] = {};
    for (int k0 = 0; k0 < K; k0 += 32) {
        uint4 av0 = make_uint4(0, 0, 0, 0), av1 = av0, bv0 = av0, bv1 = av0;
        if (a_ok) {
            av0 = *(const uint4*)(Arow + k0);
            av1 = *(const uint4*)(Arow + k0 + 8);
        }
        if (b_ok) {
            bv0 = *(const uint4*)(Brow + k0);
            bv1 = *(const uint4*)(Brow + k0 + 8);
        }
        *(uint4*)&As[srow][scol] = av0;
        *(uint4*)&As[srow][scol + 8] = av1;
        *(uint4*)&Bs[srow][scol] = bv0;
        *(uint4*)&Bs[srow][scol + 8] = bv1;
        __syncthreads();
        bf16x8 a[4], b[4];
#pragma unroll
        for (int i = 0; i < 4; i++) a[i] = *(const bf16x8*)&As[wm * 64 + i * 16 + r][q * 8];
#pragma unroll
        for (int j = 0; j < 4; j++) b[j] = *(const bf16x8*)&Bs[wn * 64 + j * 16 + r][q * 8];
#pragma unroll
        for (int i = 0; i < 4; i++)
#pragma unroll
            for (int j = 0; j < 4; j++)
                acc[i][j] = __builtin_amdgcn_mfma_f32_16x16x32_bf16(a[i], b[j], acc[i][j], 0, 0, 0);
        __syncthreads();
    }
#pragma unroll
    for (int i = 0; i < 4; i++)
#pragma unroll
        for (int j = 0; j < 4; j++)
#pragma unroll
            for (int rr = 0; rr < 4; rr++) {
                int row = m0 + wm * 64 + i * 16 + q * 4 + rr;
                int col = n0 + wn * 64 + j * 16 + r;
                if (row < M && col < Nn) {
                    float v = acc[i][j][rr];
                    if (HAS_BIAS) v += bias[col];
                    C[(size_t)row * Nn + col] = v;
                }
            }
}

// ---------------- attention logits: el/er[n,h] = <feat[n,h,:], al/ar[h,:]> ----
__global__ void attn_k(const float* __restrict__ feat, const float* __restrict__ al,
                       const float* __restrict__ ar, float* __restrict__ el,
                       float* __restrict__ er) {
    int lane = threadIdx.x & 63;
    int wave = threadIdx.x >> 6;
    int node = blockIdx.x * 4 + wave;
    if (node >= NN) return;
    int h = lane >> 4;
    const float* fp = feat + (size_t)node * HF + lane * 8;
    float4 f0 = *(const float4*)fp;
    float4 f1 = *(const float4*)(fp + 4);
    const float* alp = al + h * 128 + (lane & 15) * 8;
    const float* arp = ar + h * 128 + (lane & 15) * 8;
    float fv[8] = {f0.x, f0.y, f0.z, f0.w, f1.x, f1.y, f1.z, f1.w};
    float sl = 0.f, sr = 0.f;
#pragma unroll
    for (int j = 0; j < 8; j++) {
        sl += fv[j] * alp[j];
        sr += fv[j] * arp[j];
    }
#pragma unroll
    for (int off = 8; off >= 1; off >>= 1) {
        sl += __shfl_down(sl, off, 16);
        sr += __shfl_down(sr, off, 16);
    }
    if ((lane & 15) == 0) {
        el[node * NHEAD + h] = sl;
        er[node * NHEAD + h] = sr;
    }
}

// ---------------- CSR build: degree histogram ----------------
__global__ void deg_count_k(const int* __restrict__ dst, int* __restrict__ deg) {
    int e = blockIdx.x * blockDim.x + threadIdx.x;
    if (e < NE) atomicAdd(&deg[dst[e]], 1);
}

// ---------------- CSR build: exclusive scan (single block, 1024 thr) --------
__global__ void scan_k(const int* __restrict__ deg, int* __restrict__ off) {
    __shared__ int part[1024];
    const int CH = (NN + 1023) >> 10;  // elements per thread
    int t = threadIdx.x;
    int base = t * CH;
    int s = 0;
    for (int i = 0; i < CH; i++) {
        int idx = base + i;
        if (idx < NN) s += deg[idx];
    }
    part[t] = s;
    __syncthreads();
    for (int d = 1; d < 1024; d <<= 1) {
        int v = (t >= d) ? part[t - d] : 0;
        __syncthreads();
        part[t] += v;
        __syncthreads();
    }
    int run = (t == 0) ? 0 : part[t - 1];
    for (int i = 0; i < CH; i++) {
        int idx = base + i;
        if (idx < NN) {
            off[idx] = run;
            run += deg[idx];
        } else if (idx == NN) {
            off[NN] = run;
        }
    }
}

// ---------------- CSR build: fill sorted src list ----------------
__global__ void fill_k(const int* __restrict__ src, const int* __restrict__ dst,
                       const int* __restrict__ off, int* __restrict__ cur,
                       int* __restrict__ csrc) {
    int e = blockIdx.x * blockDim.x + threadIdx.x;
    if (e >= NE) return;
    int d = dst[e];
    int p = atomicAdd(&cur[d], 1);
    csrc[off[d] + p] = src[e];
}

// ---------------- fused: edge softmax + gather + bias + act + type-sum ------
__global__ __launch_bounds__(256) void gather_k(
    const int* __restrict__ off, const int* __restrict__ csrc,
    const float* __restrict__ el, const float* __restrict__ er,
    const float* __restrict__ feat, const float* __restrict__ bt,
    bf16* __restrict__ hout, int first, int act) {
    int lane = threadIdx.x & 63;
    int wave = threadIdx.x >> 6;
    int d = blockIdx.x * 4 + wave;
    if (d >= NN) return;
    int h = lane >> 4;
    int o0 = off[d], o1 = off[d + 1];
    float erd = er[d * NHEAD + h];

    float m = -3.0e38f;
    for (int i = o0; i < o1; i++) {
        int s = csrc[i];
        float lg = el[s * NHEAD + h] + erd;
        lg = lg > 0.f ? lg : 0.2f * lg;
        m = fmaxf(m, lg);
    }
    float sum = 0.f;
    for (int i = o0; i < o1; i++) {
        int s = csrc[i];
        float lg = el[s * NHEAD + h] + erd;
        lg = lg > 0.f ? lg : 0.2f * lg;
        sum += __expf(lg - m);
    }
    float inv = sum > 0.f ? 1.f / sum : 0.f;
    float acc[8] = {};
    for (int i = o0; i < o1; i++) {
        int s = csrc[i];
        float lg = el[s * NHEAD + h] + erd;
        lg = lg > 0.f ? lg : 0.2f * lg;
        float a = __expf(lg - m) * inv;
        const float* fp = feat + (size_t)s * HF + lane * 8;
        float4 f0 = *(const float4*)fp;
        float4 f1 = *(const float4*)(fp + 4);
        acc[0] += f0.x * a;
        acc[1] += f0.y * a;
        acc[2] += f0.z * a;
        acc[3] += f0.w * a;
        acc[4] += f1.x * a;
        acc[5] += f1.y * a;
        acc[6] += f1.z * a;
        acc[7] += f1.w * a;
    }
    const float* bp = bt + lane * 8;
    float4 b0 = *(const float4*)bp;
    float4 b1 = *(const float4*)(bp + 4);
    float bv[8] = {b0.x, b0.y, b0.z, b0.w, b1.x, b1.y, b1.z, b1.w};
    u16* hp = (u16*)(hout + (size_t)d * HF + lane * 8);
    union U8 { uint4 v; u16 s[8]; };
    U8 prev;
    if (!first) prev.v = *(const uint4*)hp;
    U8 outw;
#pragma unroll
    for (int j = 0; j < 8; j++) {
        float v = acc[j] + bv[j];
        if (act) v = v > 0.f ? v : 0.01f * v;
        if (!first) {
            bf16 pb = *(const bf16*)&prev.s[j];
            v += bf2f(pb);
        }
        bf16 ob = __float2bfloat16(v);
        outw.s[j] = *(const u16*)&ob;
    }
    *(uint4*)hp = outw.v;
}

extern "C" void kernel_launch(void* const* d_in, const int* in_sizes, int n_in,
                              void* d_out, int out_size, void* d_ws, size_t ws_size,
                              hipStream_t stream) {
    const float* x = (const float*)d_in[0];
    const int* srcs[2] = {(const int*)d_in[1], (const int*)d_in[3]};
    const int* dsts[2] = {(const int*)d_in[2], (const int*)d_in[4]};
    const float* W[3] = {(const float*)d_in[5], (const float*)d_in[9], (const float*)d_in[13]};
    const float* al[3] = {(const float*)d_in[6], (const float*)d_in[10], (const float*)d_in[14]};
    const float* ar[3] = {(const float*)d_in[7], (const float*)d_in[11], (const float*)d_in[15]};
    const float* bb[3] = {(const float*)d_in[8], (const float*)d_in[12], (const float*)d_in[16]};
    const float* Wout = (const float*)d_in[17];
    const float* bout = (const float*)d_in[18];

    // workspace layout (~170 MB)
    char* ws = (char*)d_ws;
    size_t off = 0;
    auto walloc = [&](size_t bytes) {
        void* p = ws + off;
        off = (off + bytes + 255) & ~(size_t)255;
        return p;
    };
    bf16* h0 = (bf16*)walloc((size_t)NN * HF * 2);
    bf16* h1 = (bf16*)walloc((size_t)NN * HF * 2);
    float* feat = (float*)walloc((size_t)NN * HF * 4);
    float* el = (float*)walloc((size_t)NN * NHEAD * 4);
    float* er = (float*)walloc((size_t)NN * NHEAD * 4);
    bf16* WT = (bf16*)walloc((size_t)2983 * 512 * 2);
    int* deg = (int*)walloc((size_t)NN * 4);
    int* cur = (int*)walloc((size_t)NN * 4);
    int* offs[2];
    int* csrc[2];
    for (int t = 0; t < 2; t++) {
        offs[t] = (int*)walloc((size_t)(NN + 1) * 4);
        csrc[t] = (int*)walloc((size_t)NE * 4);
    }

    // dead region of d_out used as scratch for bf16 x (out is fp32, 477 MB;
    // final GEMM overwrites everything).
    bf16* xb = (bf16*)((char*)d_out + (size_t)NN * HF * 4);

    // cast x (fp32 -> bf16) once
    cast_k<<<(NN * 1024 / 8 + 255) / 256, 256, 0, stream>>>(x, xb, NN * 1024);

    // build dst-CSR per edge type (reused across all 3 layers)
    const int EB = (NE + 255) / 256;
    for (int t = 0; t < 2; t++) {
        hipMemsetAsync(deg, 0, (size_t)NN * 4, stream);
        hipMemsetAsync(cur, 0, (size_t)NN * 4, stream);
        deg_count_k<<<EB, 256, 0, stream>>>(dsts[t], deg);
        scan_k<<<1, 1024, 0, stream>>>(deg, offs[t]);
        fill_k<<<EB, 256, 0, stream>>>(srcs[t], dsts[t], offs[t], cur, csrc[t]);
    }

    const int MT = (NN + 127) / 128;  // 313 M-tiles

    for (int l = 0; l < 3; l++) {
        const int K = (l == 0) ? 1024 : 512;
        const bf16* hin = (l == 0) ? xb : ((l == 1) ? h0 : h1);
        bf16* hout = (l == 0) ? h0 : ((l == 1) ? h1 : h0);
        const int act = (l < 2) ? 1 : 0;
        for (int t = 0; t < 2; t++) {
            // feat = hin @ W[l][t]
            transpose_k<<<dim3(512 / 32, K / 32), dim3(32, 32), 0, stream>>>(
                W[l] + (size_t)t * K * 512, WT, K, 512);
            gemm_k<false><<<dim3(512 / 128, MT), 256, 0, stream>>>(
                hin, WT, feat, nullptr, NN, 512, K);
            // logits
            attn_k<<<NN / 4, 256, 0, stream>>>(feat, al[l] + t * HF, ar[l] + t * HF, el, er);
            // fused edge-softmax + aggregate + bias + activation + type-sum
            gather_k<<<NN / 4, 256, 0, stream>>>(offs[t], csrc[t], el, er, feat,
                                                 bb[l] + t * HF, hout, t == 0 ? 1 : 0, act);
        }
    }

    // final projection: out = h @ Wout + bout   [40000 x 2983] fp32
    transpose_k<<<dim3((2983 + 31) / 32, 512 / 32), dim3(32, 32), 0, stream>>>(
        Wout, WT, 512, 2983);
    gemm_k<true><<<dim3((2983 + 127) / 128, MT), 256, 0, stream>>>(
        h0, WT, (float*)d_out, bout, NN, 2983, 512);
}

// Round 3
// 1764.348 us; speedup vs baseline: 8.0976x; 1.0266x over previous
//
#include <hip/hip_runtime.h>
#include <hip/hip_bf16.h>

#define NN 40000      // nodes
#define NE 150000     // edges per type
#define HF 512        // H*D
#define NHEAD 4

typedef __bf16 bf16x8 __attribute__((ext_vector_type(8)));
typedef float floatx4 __attribute__((ext_vector_type(4)));
typedef __hip_bfloat16 bf16;
typedef unsigned short u16;

__device__ __forceinline__ float bf2f(bf16 v) { return __bfloat162float(v); }

// async global->LDS DMA, 16B per lane. ldsbase must be wave-uniform;
// HW writes lane i's 16B at ldsbase + i*16 (linear, no per-lane scatter).
__device__ __forceinline__ void gload16(const void* g, void* l) {
    __builtin_amdgcn_global_load_lds(
        (const __attribute__((address_space(1))) void*)g,
        (__attribute__((address_space(3))) void*)l, 16, 0, 0);
}

// ---------------- cast fp32 -> bf16, elementwise (8/thread, 16B stores) -----
__global__ void cast_k(const float* __restrict__ in, bf16* __restrict__ out, int n) {
    int i = (blockIdx.x * blockDim.x + threadIdx.x) * 8;
    if (i + 7 < n) {
        float4 v0 = *(const float4*)(in + i);
        float4 v1 = *(const float4*)(in + i + 4);
        union { uint4 u; u16 s[8]; } w;
        float fv[8] = {v0.x, v0.y, v0.z, v0.w, v1.x, v1.y, v1.z, v1.w};
#pragma unroll
        for (int j = 0; j < 8; j++) {
            bf16 b = __float2bfloat16(fv[j]);
            w.s[j] = *(const u16*)&b;
        }
        *(uint4*)(out + i) = w.u;
    } else {
        for (int j = i; j < n; j++) out[j] = __float2bfloat16(in[j]);
    }
}

// ---------------- transpose+cast: WT[n*K+k] = bf16(W[k*N+n]) ----------------
__global__ void transpose_k(const float* __restrict__ W, bf16* __restrict__ WT,
                            int K, int Nn) {
    __shared__ float tile[32][33];
    int n0 = blockIdx.x * 32, k0 = blockIdx.y * 32;
    int tx = threadIdx.x, ty = threadIdx.y;
    int n = n0 + tx, k = k0 + ty;
    if (n < Nn && k < K) tile[ty][tx] = W[(size_t)k * Nn + n];
    __syncthreads();
    int nn = n0 + ty, kk = k0 + tx;
    if (nn < Nn && kk < K) WT[(size_t)nn * K + kk] = __float2bfloat16(tile[tx][ty]);
}

// ---------------- GEMM: C[M,Nn] = A[M,K] * BT[Nn,K]^T ----------------
// 128x128 tile, BK=32, 4 waves (2x2), each wave 64x64 = 4x4 frags 16x16x32.
// Staging via global_load_lds width=16 into LINEAR [128][32] LDS (m97 form).
// grid: (ntiles, mtiles) — blockIdx.x walks N so consecutive blocks share the
// A row-panel; bijective XCD swizzle keeps panel-sharers on one XCD L2.
template <bool HAS_BIAS>
__global__ __launch_bounds__(256) void gemm_k(const bf16* __restrict__ A,
                                              const bf16* __restrict__ BT,
                                              float* __restrict__ C,
                                              const float* __restrict__ bias,
                                              int M, int Nn, int K) {
    __shared__ __align__(16) unsigned short As[128][32];
    __shared__ __align__(16) unsigned short Bs[128][32];

    // bijective XCD swizzle (m204 form; handles nwg % 8 != 0)
    const int nwg = gridDim.x * gridDim.y;
    const int orig = blockIdx.y * gridDim.x + blockIdx.x;
    const int qq = nwg >> 3, r8 = nwg & 7;
    const int xcd = orig & 7, loc = orig >> 3;
    const int swz = (xcd < r8 ? xcd * (qq + 1) : r8 * (qq + 1) + (xcd - r8) * qq) + loc;
    const int ntile = swz % gridDim.x;
    const int mtile = swz / gridDim.x;
    const int m0 = mtile * 128;
    const int n0 = ntile * 128;

    const int t = threadIdx.x;
    const int lane = t & 63;
    const int wave = t >> 6;
    const int wm = wave >> 1, wn = wave & 1;
    const int q = lane >> 4, r = lane & 15;

    // staging geometry: wave w stages LDS bytes [w*2048, w*2048+2048) of each
    // tile in 2 rounds of 1024B (64 lanes x 16B). byte o -> row=o>>6,
    // col=(o&63)>>1. Round p adds 16 rows.
    const int srow = wave * 32 + (lane >> 2);   // row for round 0
    const int scol = (lane & 3) * 8;            // col in elements (16B chunks)
    int ar0 = m0 + srow;        if (ar0 >= M)  ar0 = M - 1;
    int ar1 = m0 + srow + 16;   if (ar1 >= M)  ar1 = M - 1;
    int br0 = n0 + srow;        if (br0 >= Nn) br0 = Nn - 1;
    int br1 = n0 + srow + 16;   if (br1 >= Nn) br1 = Nn - 1;
    const unsigned short* Ag0 = (const unsigned short*)A + (size_t)ar0 * K + scol;
    const unsigned short* Ag1 = (const unsigned short*)A + (size_t)ar1 * K + scol;
    const unsigned short* Bg0 = (const unsigned short*)BT + (size_t)br0 * K + scol;
    const unsigned short* Bg1 = (const unsigned short*)BT + (size_t)br1 * K + scol;
    // wave-uniform LDS bases (bytes: wave*2048, +1024 for round 1)
    unsigned short* Al0 = &As[0][0] + wave * 1024;
    unsigned short* Al1 = Al0 + 512;
    unsigned short* Bl0 = &Bs[0][0] + wave * 1024;
    unsigned short* Bl1 = Bl0 + 512;

    floatx4 acc[4][4] = {};
    for (int k0 = 0; k0 < K; k0 += 32) {
        gload16(Ag0 + k0, Al0);
        gload16(Ag1 + k0, Al1);
        gload16(Bg0 + k0, Bl0);
        gload16(Bg1 + k0, Bl1);
        __syncthreads();   // drains vmcnt -> LDS tiles complete
        bf16x8 a[4], b[4];
#pragma unroll
        for (int i = 0; i < 4; i++) a[i] = *(const bf16x8*)&As[wm * 64 + i * 16 + r][q * 8];
#pragma unroll
        for (int j = 0; j < 4; j++) b[j] = *(const bf16x8*)&Bs[wn * 64 + j * 16 + r][q * 8];
#pragma unroll
        for (int i = 0; i < 4; i++)
#pragma unroll
            for (int j = 0; j < 4; j++)
                acc[i][j] = __builtin_amdgcn_mfma_f32_16x16x32_bf16(a[i], b[j], acc[i][j], 0, 0, 0);
        __syncthreads();
    }
#pragma unroll
    for (int i = 0; i < 4; i++)
#pragma unroll
        for (int j = 0; j < 4; j++)
#pragma unroll
            for (int rr = 0; rr < 4; rr++) {
                int row = m0 + wm * 64 + i * 16 + q * 4 + rr;
                int col = n0 + wn * 64 + j * 16 + r;
                if (row < M && col < Nn) {
                    float v = acc[i][j][rr];
                    if (HAS_BIAS) v += bias[col];
                    C[(size_t)row * Nn + col] = v;
                }
            }
}

// ---------------- attention logits: el/er[n,h] = <feat[n,h,:], al/ar[h,:]> ----
__global__ void attn_k(const float* __restrict__ feat, const float* __restrict__ al,
                       const float* __restrict__ ar, float* __restrict__ el,
                       float* __restrict__ er) {
    int lane = threadIdx.x & 63;
    int wave = threadIdx.x >> 6;
    int node = blockIdx.x * 4 + wave;
    if (node >= NN) return;
    int h = lane >> 4;
    const float* fp = feat + (size_t)node * HF + lane * 8;
    float4 f0 = *(const float4*)fp;
    float4 f1 = *(const float4*)(fp + 4);
    const float* alp = al + h * 128 + (lane & 15) * 8;
    const float* arp = ar + h * 128 + (lane & 15) * 8;
    float fv[8] = {f0.x, f0.y, f0.z, f0.w, f1.x, f1.y, f1.z, f1.w};
    float sl = 0.f, sr = 0.f;
#pragma unroll
    for (int j = 0; j < 8; j++) {
        sl += fv[j] * alp[j];
        sr += fv[j] * arp[j];
    }
#pragma unroll
    for (int off = 8; off >= 1; off >>= 1) {
        sl += __shfl_down(sl, off, 16);
        sr += __shfl_down(sr, off, 16);
    }
    if ((lane & 15) == 0) {
        el[node * NHEAD + h] = sl;
        er[node * NHEAD + h] = sr;
    }
}

// ---------------- CSR build: degree histogram ----------------
__global__ void deg_count_k(const int* __restrict__ dst, int* __restrict__ deg) {
    int e = blockIdx.x * blockDim.x + threadIdx.x;
    if (e < NE) atomicAdd(&deg[dst[e]], 1);
}

// ---------------- CSR build: exclusive scan (single block, 1024 thr) --------
__global__ void scan_k(const int* __restrict__ deg, int* __restrict__ off) {
    __shared__ int part[1024];
    const int CH = (NN + 1023) >> 10;  // elements per thread
    int t = threadIdx.x;
    int base = t * CH;
    int s = 0;
    for (int i = 0; i < CH; i++) {
        int idx = base + i;
        if (idx < NN) s += deg[idx];
    }
    part[t] = s;
    __syncthreads();
    for (int d = 1; d < 1024; d <<= 1) {
        int v = (t >= d) ? part[t - d] : 0;
        __syncthreads();
        part[t] += v;
        __syncthreads();
    }
    int run = (t == 0) ? 0 : part[t - 1];
    for (int i = 0; i < CH; i++) {
        int idx = base + i;
        if (idx < NN) {
            off[idx] = run;
            run += deg[idx];
        } else if (idx == NN) {
            off[NN] = run;
        }
    }
}

// ---------------- CSR build: fill sorted src list ----------------
__global__ void fill_k(const int* __restrict__ src, const int* __restrict__ dst,
                       const int* __restrict__ off, int* __restrict__ cur,
                       int* __restrict__ csrc) {
    int e = blockIdx.x * blockDim.x + threadIdx.x;
    if (e >= NE) return;
    int d = dst[e];
    int p = atomicAdd(&cur[d], 1);
    csrc[off[d] + p] = src[e];
}

// ---------------- fused: edge softmax + gather + bias + act + type-sum ------
__global__ __launch_bounds__(256) void gather_k(
    const int* __restrict__ off, const int* __restrict__ csrc,
    const float* __restrict__ el, const float* __restrict__ er,
    const float* __restrict__ feat, const float* __restrict__ bt,
    bf16* __restrict__ hout, int first, int act) {
    int lane = threadIdx.x & 63;
    int wave = threadIdx.x >> 6;
    int d = blockIdx.x * 4 + wave;
    if (d >= NN) return;
    int h = lane >> 4;
    int o0 = off[d], o1 = off[d + 1];
    float erd = er[d * NHEAD + h];

    // pass 1: online segment max + exp-sum (single loop)
    float m = -3.0e38f, sum = 0.f;
    for (int i = o0; i < o1; i++) {
        int s = csrc[i];
        float lg = el[s * NHEAD + h] + erd;
        lg = lg > 0.f ? lg : 0.2f * lg;
        float mn = fmaxf(m, lg);
        sum = sum * __expf(m - mn) + __expf(lg - mn);
        m = mn;
    }
    float inv = sum > 0.f ? 1.f / sum : 0.f;
    // pass 2: weighted gather into registers
    float acc[8] = {};
    for (int i = o0; i < o1; i++) {
        int s = csrc[i];
        float lg = el[s * NHEAD + h] + erd;
        lg = lg > 0.f ? lg : 0.2f * lg;
        float a = __expf(lg - m) * inv;
        const float* fp = feat + (size_t)s * HF + lane * 8;
        float4 f0 = *(const float4*)fp;
        float4 f1 = *(const float4*)(fp + 4);
        acc[0] += f0.x * a;
        acc[1] += f0.y * a;
        acc[2] += f0.z * a;
        acc[3] += f0.w * a;
        acc[4] += f1.x * a;
        acc[5] += f1.y * a;
        acc[6] += f1.z * a;
        acc[7] += f1.w * a;
    }
    const float* bp = bt + lane * 8;
    float4 b0 = *(const float4*)bp;
    float4 b1 = *(const float4*)(bp + 4);
    float bv[8] = {b0.x, b0.y, b0.z, b0.w, b1.x, b1.y, b1.z, b1.w};
    u16* hp = (u16*)(hout + (size_t)d * HF + lane * 8);
    union U8 { uint4 v; u16 s[8]; };
    U8 prev;
    if (!first) prev.v = *(const uint4*)hp;
    U8 outw;
#pragma unroll
    for (int j = 0; j < 8; j++) {
        float v = acc[j] + bv[j];
        if (act) v = v > 0.f ? v : 0.01f * v;
        if (!first) {
            bf16 pb = *(const bf16*)&prev.s[j];
            v += bf2f(pb);
        }
        bf16 ob = __float2bfloat16(v);
        outw.s[j] = *(const u16*)&ob;
    }
    *(uint4*)hp = outw.v;
}

extern "C" void kernel_launch(void* const* d_in, const int* in_sizes, int n_in,
                              void* d_out, int out_size, void* d_ws, size_t ws_size,
                              hipStream_t stream) {
    const float* x = (const float*)d_in[0];
    const int* srcs[2] = {(const int*)d_in[1], (const int*)d_in[3]};
    const int* dsts[2] = {(const int*)d_in[2], (const int*)d_in[4]};
    const float* W[3] = {(const float*)d_in[5], (const float*)d_in[9], (const float*)d_in[13]};
    const float* al[3] = {(const float*)d_in[6], (const float*)d_in[10], (const float*)d_in[14]};
    const float* ar[3] = {(const float*)d_in[7], (const float*)d_in[11], (const float*)d_in[15]};
    const float* bb[3] = {(const float*)d_in[8], (const float*)d_in[12], (const float*)d_in[16]};
    const float* Wout = (const float*)d_in[17];
    const float* bout = (const float*)d_in[18];

    // workspace layout (~170 MB)
    char* ws = (char*)d_ws;
    size_t off = 0;
    auto walloc = [&](size_t bytes) {
        void* p = ws + off;
        off = (off + bytes + 255) & ~(size_t)255;
        return p;
    };
    bf16* h0 = (bf16*)walloc((size_t)NN * HF * 2);
    bf16* h1 = (bf16*)walloc((size_t)NN * HF * 2);
    float* feat = (float*)walloc((size_t)NN * HF * 4);
    float* el = (float*)walloc((size_t)NN * NHEAD * 4);
    float* er = (float*)walloc((size_t)NN * NHEAD * 4);
    bf16* WT = (bf16*)walloc((size_t)2983 * 512 * 2);
    int* deg = (int*)walloc((size_t)NN * 4);
    int* cur = (int*)walloc((size_t)NN * 4);
    int* offs[2];
    int* csrc[2];
    for (int t = 0; t < 2; t++) {
        offs[t] = (int*)walloc((size_t)(NN + 1) * 4);
        csrc[t] = (int*)walloc((size_t)NE * 4);
    }

    // dead region of d_out used as scratch for bf16 x (out is fp32, 477 MB;
    // final GEMM overwrites everything).
    bf16* xb = (bf16*)((char*)d_out + (size_t)NN * HF * 4);

    // cast x (fp32 -> bf16) once
    cast_k<<<(NN * 1024 / 8 + 255) / 256, 256, 0, stream>>>(x, xb, NN * 1024);

    // build dst-CSR per edge type (reused across all 3 layers)
    const int EB = (NE + 255) / 256;
    for (int t = 0; t < 2; t++) {
        hipMemsetAsync(deg, 0, (size_t)NN * 4, stream);
        hipMemsetAsync(cur, 0, (size_t)NN * 4, stream);
        deg_count_k<<<EB, 256, 0, stream>>>(dsts[t], deg);
        scan_k<<<1, 1024, 0, stream>>>(deg, offs[t]);
        fill_k<<<EB, 256, 0, stream>>>(srcs[t], dsts[t], offs[t], cur, csrc[t]);
    }

    const int MT = (NN + 127) / 128;  // 313 M-tiles

    for (int l = 0; l < 3; l++) {
        const int K = (l == 0) ? 1024 : 512;
        const bf16* hin = (l == 0) ? xb : ((l == 1) ? h0 : h1);
        bf16* hout = (l == 0) ? h0 : ((l == 1) ? h1 : h0);
        const int act = (l < 2) ? 1 : 0;
        for (int t = 0; t < 2; t++) {
            // feat = hin @ W[l][t]
            transpose_k<<<dim3(512 / 32, K / 32), dim3(32, 32), 0, stream>>>(
                W[l] + (size_t)t * K * 512, WT, K, 512);
            gemm_k<false><<<dim3(512 / 128, MT), 256, 0, stream>>>(
                hin, WT, feat, nullptr, NN, 512, K);
            // logits
            attn_k<<<NN / 4, 256, 0, stream>>>(feat, al[l] + t * HF, ar[l] + t * HF, el, er);
            // fused edge-softmax + aggregate + bias + activation + type-sum
            gather_k<<<NN / 4, 256, 0, stream>>>(offs[t], csrc[t], el, er, feat,
                                                 bb[l] + t * HF, hout, t == 0 ? 1 : 0, act);
        }
    }

    // final projection: out = h @ Wout + bout   [40000 x 2983] fp32
    transpose_k<<<dim3((2983 + 31) / 32, 512 / 32), dim3(32, 32), 0, stream>>>(
        Wout, WT, 512, 2983);
    gemm_k<true><<<dim3((2983 + 127) / 128, MT), 256, 0, stream>>>(
        h0, WT, (float*)d_out, bout, NN, 2983, 512);
}

// Round 5
// 1699.628 us; speedup vs baseline: 8.4059x; 1.0381x over previous
//
#include <hip/hip_runtime.h>
#include <hip/hip_bf16.h>

#define NN 40000      // nodes
#define NE 150000     // edges per type
#define HF 512        // H*D
#define NHEAD 4

typedef __bf16 bf16x8 __attribute__((ext_vector_type(8)));
typedef float floatx4 __attribute__((ext_vector_type(4)));
typedef __hip_bfloat16 bf16;
typedef unsigned short u16;

__device__ __forceinline__ float bf2f(bf16 v) { return __bfloat162float(v); }

// async global->LDS DMA, 16B per lane. ldsbase must be wave-uniform;
// HW writes lane i's 16B at ldsbase + i*16 (linear, no per-lane scatter).
__device__ __forceinline__ void gload16(const void* g, void* l) {
    __builtin_amdgcn_global_load_lds(
        (const __attribute__((address_space(1))) void*)g,
        (__attribute__((address_space(3))) void*)l, 16, 0, 0);
}

// explicit drain of outstanding global_load_lds before a barrier.
// __syncthreads alone does NOT order the intrinsic's async LDS write
// (workgroup fence only waits lgkmcnt) -> race without this (round-4 lesson).
__device__ __forceinline__ void wait_vm0() {
    asm volatile("s_waitcnt vmcnt(0)" ::: "memory");
}

// ---------------- cast fp32 -> bf16, elementwise (8/thread, 16B stores) -----
__global__ void cast_k(const float* __restrict__ in, bf16* __restrict__ out, int n) {
    int i = (blockIdx.x * blockDim.x + threadIdx.x) * 8;
    if (i + 7 < n) {
        float4 v0 = *(const float4*)(in + i);
        float4 v1 = *(const float4*)(in + i + 4);
        union { uint4 u; u16 s[8]; } w;
        float fv[8] = {v0.x, v0.y, v0.z, v0.w, v1.x, v1.y, v1.z, v1.w};
#pragma unroll
        for (int j = 0; j < 8; j++) {
            bf16 b = __float2bfloat16(fv[j]);
            w.s[j] = *(const u16*)&b;
        }
        *(uint4*)(out + i) = w.u;
    } else {
        for (int j = i; j < n; j++) out[j] = __float2bfloat16(in[j]);
    }
}

// ---------------- transpose+cast: WT[n*K+k] = bf16(W[k*N+n]) ----------------
__global__ void transpose_k(const float* __restrict__ W, bf16* __restrict__ WT,
                            int K, int Nn) {
    __shared__ float tile[32][33];
    int n0 = blockIdx.x * 32, k0 = blockIdx.y * 32;
    int tx = threadIdx.x, ty = threadIdx.y;
    int n = n0 + tx, k = k0 + ty;
    if (n < Nn && k < K) tile[ty][tx] = W[(size_t)k * Nn + n];
    __syncthreads();
    int nn = n0 + ty, kk = k0 + tx;
    if (nn < Nn && kk < K) WT[(size_t)nn * K + kk] = __float2bfloat16(tile[tx][ty]);
}

// ---------------- GEMM: C[M,Nn] = A[M,K] * BT[Nn,K]^T ----------------
// 128x128 tile, BK=32, 4 waves (2x2), each wave 64x64 = 4x4 frags 16x16x32.
// Staging: global_load_lds width=16 into LINEAR double-buffered [128][32] LDS.
// Bank-conflict-free via source-side XOR swizzle: LDS slot (row, c) holds
// global 16B-chunk (c ^ ((row>>1)&3)); reads apply the same XOR -> 2-way max.
// 2-phase pipeline: next tile's loads issue before current tile's MFMAs;
// explicit s_waitcnt vmcnt(0) before the barrier drains them (T3 recipe).
// grid: (ntiles, mtiles) — blockIdx.x walks N so consecutive blocks share the
// A row-panel; bijective XCD swizzle keeps panel-sharers on one XCD L2.
template <bool HAS_BIAS>
__global__ __launch_bounds__(256) void gemm_k(const bf16* __restrict__ A,
                                              const bf16* __restrict__ BT,
                                              float* __restrict__ C,
                                              const float* __restrict__ bias,
                                              int M, int Nn, int K) {
    __shared__ __align__(16) unsigned short As[2][128][32];
    __shared__ __align__(16) unsigned short Bs[2][128][32];

    // bijective XCD swizzle (m204 form; handles nwg % 8 != 0)
    const int nwg = gridDim.x * gridDim.y;
    const int orig = blockIdx.y * gridDim.x + blockIdx.x;
    const int qq = nwg >> 3, r8 = nwg & 7;
    const int xcd = orig & 7, loc = orig >> 3;
    const int swz = (xcd < r8 ? xcd * (qq + 1) : r8 * (qq + 1) + (xcd - r8) * qq) + loc;
    const int ntile = swz % gridDim.x;
    const int mtile = swz / gridDim.x;
    const int m0 = mtile * 128;
    const int n0 = ntile * 128;

    const int t = threadIdx.x;
    const int lane = t & 63;
    const int wave = t >> 6;
    const int wm = wave >> 1, wn = wave & 1;
    const int q = lane >> 4, r = lane & 15;

    // staging geometry: wave w stages rows [w*32, w*32+32) in 2 rounds of 16
    // rows (64 lanes x 16B = 1KB linear). Lane l -> slot row w*32+(l>>2)
    // (+16 round 1), slot chunk l&3. Source chunk = (l&3) ^ ((srow>>1)&3)
    // (same XOR key for both rounds: +16 rows -> +8 after >>1 -> 0 mod 4).
    const int srow = wave * 32 + (lane >> 2);
    const int scol = ((lane & 3) ^ ((srow >> 1) & 3)) * 8;  // element offset
    int ar0 = m0 + srow;        if (ar0 >= M)  ar0 = M - 1;
    int ar1 = m0 + srow + 16;   if (ar1 >= M)  ar1 = M - 1;
    int br0 = n0 + srow;        if (br0 >= Nn) br0 = Nn - 1;
    int br1 = n0 + srow + 16;   if (br1 >= Nn) br1 = Nn - 1;
    const unsigned short* Ag0 = (const unsigned short*)A + (size_t)ar0 * K + scol;
    const unsigned short* Ag1 = (const unsigned short*)A + (size_t)ar1 * K + scol;
    const unsigned short* Bg0 = (const unsigned short*)BT + (size_t)br0 * K + scol;
    const unsigned short* Bg1 = (const unsigned short*)BT + (size_t)br1 * K + scol;
    // wave-uniform LDS bases (shorts): wave*1024 within each buffer
    unsigned short* Alb[2] = {&As[0][0][0] + wave * 1024, &As[1][0][0] + wave * 1024};
    unsigned short* Blb[2] = {&Bs[0][0][0] + wave * 1024, &Bs[1][0][0] + wave * 1024};

    // fragment-read chunk offsets (elements), same XOR as staging
    const int rchunk = (q ^ ((r >> 1) & 3)) * 8;

    floatx4 acc[4][4] = {};
    const int nt = K >> 5;
    int cur = 0;
    // prologue: stage tile 0
    gload16(Ag0, Alb[0]);
    gload16(Ag1, Alb[0] + 512);
    gload16(Bg0, Blb[0]);
    gload16(Bg1, Blb[0] + 512);
    wait_vm0();
    __syncthreads();
    for (int tt = 0; tt < nt; tt++) {
        if (tt + 1 < nt) {
            const int k1 = (tt + 1) << 5;
            gload16(Ag0 + k1, Alb[cur ^ 1]);
            gload16(Ag1 + k1, Alb[cur ^ 1] + 512);
            gload16(Bg0 + k1, Blb[cur ^ 1]);
            gload16(Bg1 + k1, Blb[cur ^ 1] + 512);
        }
        bf16x8 a[4], b[4];
#pragma unroll
        for (int i = 0; i < 4; i++)
            a[i] = *(const bf16x8*)&As[cur][wm * 64 + i * 16 + r][rchunk];
#pragma unroll
        for (int j = 0; j < 4; j++)
            b[j] = *(const bf16x8*)&Bs[cur][wn * 64 + j * 16 + r][rchunk];
#pragma unroll
        for (int i = 0; i < 4; i++)
#pragma unroll
            for (int j = 0; j < 4; j++)
                acc[i][j] = __builtin_amdgcn_mfma_f32_16x16x32_bf16(a[i], b[j], acc[i][j], 0, 0, 0);
        wait_vm0();        // prefetched tile fully landed in LDS
        __syncthreads();   // now safe for all waves to swap buffers
        cur ^= 1;
    }

    // hoisted bias (4 columns per thread)
    float bv4[4] = {0.f, 0.f, 0.f, 0.f};
    if (HAS_BIAS) {
#pragma unroll
        for (int j = 0; j < 4; j++) {
            int col = n0 + wn * 64 + j * 16 + r;
            if (col < Nn) bv4[j] = bias[col];
        }
    }
#pragma unroll
    for (int i = 0; i < 4; i++)
#pragma unroll
        for (int j = 0; j < 4; j++)
#pragma unroll
            for (int rr = 0; rr < 4; rr++) {
                int row = m0 + wm * 64 + i * 16 + q * 4 + rr;
                int col = n0 + wn * 64 + j * 16 + r;
                if (row < M && col < Nn) {
                    float v = acc[i][j][rr];
                    if (HAS_BIAS) v += bv4[j];
                    C[(size_t)row * Nn + col] = v;
                }
            }
}

// ---------------- attention logits: el/er[n,h] = <feat[n,h,:], al/ar[h,:]> ----
__global__ void attn_k(const float* __restrict__ feat, const float* __restrict__ al,
                       const float* __restrict__ ar, float* __restrict__ el,
                       float* __restrict__ er) {
    int lane = threadIdx.x & 63;
    int wave = threadIdx.x >> 6;
    int node = blockIdx.x * 4 + wave;
    if (node >= NN) return;
    int h = lane >> 4;
    const float* fp = feat + (size_t)node * HF + lane * 8;
    float4 f0 = *(const float4*)fp;
    float4 f1 = *(const float4*)(fp + 4);
    const float* alp = al + h * 128 + (lane & 15) * 8;
    const float* arp = ar + h * 128 + (lane & 15) * 8;
    float fv[8] = {f0.x, f0.y, f0.z, f0.w, f1.x, f1.y, f1.z, f1.w};
    float sl = 0.f, sr = 0.f;
#pragma unroll
    for (int j = 0; j < 8; j++) {
        sl += fv[j] * alp[j];
        sr += fv[j] * arp[j];
    }
#pragma unroll
    for (int off = 8; off >= 1; off >>= 1) {
        sl += __shfl_down(sl, off, 16);
        sr += __shfl_down(sr, off, 16);
    }
    if ((lane & 15) == 0) {
        el[node * NHEAD + h] = sl;
        er[node * NHEAD + h] = sr;
    }
}

// ---------------- CSR build: degree histogram ----------------
__global__ void deg_count_k(const int* __restrict__ dst, int* __restrict__ deg) {
    int e = blockIdx.x * blockDim.x + threadIdx.x;
    if (e < NE) atomicAdd(&deg[dst[e]], 1);
}

// ---------------- CSR build: exclusive scan (single block, 1024 thr) --------
__global__ void scan_k(const int* __restrict__ deg, int* __restrict__ off) {
    __shared__ int part[1024];
    const int CH = (NN + 1023) >> 10;  // elements per thread
    int t = threadIdx.x;
    int base = t * CH;
    int s = 0;
    for (int i = 0; i < CH; i++) {
        int idx = base + i;
        if (idx < NN) s += deg[idx];
    }
    part[t] = s;
    __syncthreads();
    for (int d = 1; d < 1024; d <<= 1) {
        int v = (t >= d) ? part[t - d] : 0;
        __syncthreads();
        part[t] += v;
        __syncthreads();
    }
    int run = (t == 0) ? 0 : part[t - 1];
    for (int i = 0; i < CH; i++) {
        int idx = base + i;
        if (idx < NN) {
            off[idx] = run;
            run += deg[idx];
        } else if (idx == NN) {
            off[NN] = run;
        }
    }
}

// ---------------- CSR build: fill sorted src list ----------------
__global__ void fill_k(const int* __restrict__ src, const int* __restrict__ dst,
                       const int* __restrict__ off, int* __restrict__ cur,
                       int* __restrict__ csrc) {
    int e = blockIdx.x * blockDim.x + threadIdx.x;
    if (e >= NE) return;
    int d = dst[e];
    int p = atomicAdd(&cur[d], 1);
    csrc[off[d] + p] = src[e];
}

// ---------------- fused: edge softmax + gather + bias + act + type-sum ------
__global__ __launch_bounds__(256) void gather_k(
    const int* __restrict__ off, const int* __restrict__ csrc,
    const float* __restrict__ el, const float* __restrict__ er,
    const float* __restrict__ feat, const float* __restrict__ bt,
    bf16* __restrict__ hout, int first, int act) {
    int lane = threadIdx.x & 63;
    int wave = threadIdx.x >> 6;
    int d = blockIdx.x * 4 + wave;
    if (d >= NN) return;
    int h = lane >> 4;
    int o0 = off[d], o1 = off[d + 1];
    float erd = er[d * NHEAD + h];

    // pass 1: online segment max + exp-sum (single loop)
    float m = -3.0e38f, sum = 0.f;
    for (int i = o0; i < o1; i++) {
        int s = csrc[i];
        float lg = el[s * NHEAD + h] + erd;
        lg = lg > 0.f ? lg : 0.2f * lg;
        float mn = fmaxf(m, lg);
        sum = sum * __expf(m - mn) + __expf(lg - mn);
        m = mn;
    }
    float inv = sum > 0.f ? 1.f / sum : 0.f;
    // pass 2: weighted gather into registers
    float acc[8] = {};
    for (int i = o0; i < o1; i++) {
        int s = csrc[i];
        float lg = el[s * NHEAD + h] + erd;
        lg = lg > 0.f ? lg : 0.2f * lg;
        float a = __expf(lg - m) * inv;
        const float* fp = feat + (size_t)s * HF + lane * 8;
        float4 f0 = *(const float4*)fp;
        float4 f1 = *(const float4*)(fp + 4);
        acc[0] += f0.x * a;
        acc[1] += f0.y * a;
        acc[2] += f0.z * a;
        acc[3] += f0.w * a;
        acc[4] += f1.x * a;
        acc[5] += f1.y * a;
        acc[6] += f1.z * a;
        acc[7] += f1.w * a;
    }
    const float* bp = bt + lane * 8;
    float4 b0 = *(const float4*)bp;
    float4 b1 = *(const float4*)(bp + 4);
    float bv[8] = {b0.x, b0.y, b0.z, b0.w, b1.x, b1.y, b1.z, b1.w};
    u16* hp = (u16*)(hout + (size_t)d * HF + lane * 8);
    union U8 { uint4 v; u16 s[8]; };
    U8 prev;
    if (!first) prev.v = *(const uint4*)hp;
    U8 outw;
#pragma unroll
    for (int j = 0; j < 8; j++) {
        float v = acc[j] + bv[j];
        if (act) v = v > 0.f ? v : 0.01f * v;
        if (!first) {
            bf16 pb = *(const bf16*)&prev.s[j];
            v += bf2f(pb);
        }
        bf16 ob = __float2bfloat16(v);
        outw.s[j] = *(const u16*)&ob;
    }
    *(uint4*)hp = outw.v;
}

extern "C" void kernel_launch(void* const* d_in, const int* in_sizes, int n_in,
                              void* d_out, int out_size, void* d_ws, size_t ws_size,
                              hipStream_t stream) {
    const float* x = (const float*)d_in[0];
    const int* srcs[2] = {(const int*)d_in[1], (const int*)d_in[3]};
    const int* dsts[2] = {(const int*)d_in[2], (const int*)d_in[4]};
    const float* W[3] = {(const float*)d_in[5], (const float*)d_in[9], (const float*)d_in[13]};
    const float* al[3] = {(const float*)d_in[6], (const float*)d_in[10], (const float*)d_in[14]};
    const float* ar[3] = {(const float*)d_in[7], (const float*)d_in[11], (const float*)d_in[15]};
    const float* bb[3] = {(const float*)d_in[8], (const float*)d_in[12], (const float*)d_in[16]};
    const float* Wout = (const float*)d_in[17];
    const float* bout = (const float*)d_in[18];

    // workspace layout (~170 MB)
    char* ws = (char*)d_ws;
    size_t off = 0;
    auto walloc = [&](size_t bytes) {
        void* p = ws + off;
        off = (off + bytes + 255) & ~(size_t)255;
        return p;
    };
    bf16* h0 = (bf16*)walloc((size_t)NN * HF * 2);
    bf16* h1 = (bf16*)walloc((size_t)NN * HF * 2);
    float* feat = (float*)walloc((size_t)NN * HF * 4);
    float* el = (float*)walloc((size_t)NN * NHEAD * 4);
    float* er = (float*)walloc((size_t)NN * NHEAD * 4);
    bf16* WT = (bf16*)walloc((size_t)2983 * 512 * 2);
    int* deg = (int*)walloc((size_t)NN * 4);
    int* cur = (int*)walloc((size_t)NN * 4);
    int* offs[2];
    int* csrc[2];
    for (int t = 0; t < 2; t++) {
        offs[t] = (int*)walloc((size_t)(NN + 1) * 4);
        csrc[t] = (int*)walloc((size_t)NE * 4);
    }

    // dead region of d_out used as scratch for bf16 x (out is fp32, 477 MB;
    // final GEMM overwrites everything).
    bf16* xb = (bf16*)((char*)d_out + (size_t)NN * HF * 4);

    // cast x (fp32 -> bf16) once
    cast_k<<<(NN * 1024 / 8 + 255) / 256, 256, 0, stream>>>(x, xb, NN * 1024);

    // build dst-CSR per edge type (reused across all 3 layers)
    const int EB = (NE + 255) / 256;
    for (int t = 0; t < 2; t++) {
        hipMemsetAsync(deg, 0, (size_t)NN * 4, stream);
        hipMemsetAsync(cur, 0, (size_t)NN * 4, stream);
        deg_count_k<<<EB, 256, 0, stream>>>(dsts[t], deg);
        scan_k<<<1, 1024, 0, stream>>>(deg, offs[t]);
        fill_k<<<EB, 256, 0, stream>>>(srcs[t], dsts[t], offs[t], cur, csrc[t]);
    }

    const int MT = (NN + 127) / 128;  // 313 M-tiles

    for (int l = 0; l < 3; l++) {
        const int K = (l == 0) ? 1024 : 512;
        const bf16* hin = (l == 0) ? xb : ((l == 1) ? h0 : h1);
        bf16* hout = (l == 0) ? h0 : ((l == 1) ? h1 : h0);
        const int act = (l < 2) ? 1 : 0;
        for (int t = 0; t < 2; t++) {
            // feat = hin @ W[l][t]
            transpose_k<<<dim3(512 / 32, K / 32), dim3(32, 32), 0, stream>>>(
                W[l] + (size_t)t * K * 512, WT, K, 512);
            gemm_k<false><<<dim3(512 / 128, MT), 256, 0, stream>>>(
                hin, WT, feat, nullptr, NN, 512, K);
            // logits
            attn_k<<<NN / 4, 256, 0, stream>>>(feat, al[l] + t * HF, ar[l] + t * HF, el, er);
            // fused edge-softmax + aggregate + bias + activation + type-sum
            gather_k<<<NN / 4, 256, 0, stream>>>(offs[t], csrc[t], el, er, feat,
                                                 bb[l] + t * HF, hout, t == 0 ? 1 : 0, act);
        }
    }

    // final projection: out = h @ Wout + bout   [40000 x 2983] fp32
    transpose_k<<<dim3((2983 + 31) / 32, 512 / 32), dim3(32, 32), 0, stream>>>(
        Wout, WT, 512, 2983);
    gemm_k<true><<<dim3((2983 + 127) / 128, MT), 256, 0, stream>>>(
        h0, WT, (float*)d_out, bout, NN, 2983, 512);
}

// Round 6
// 1578.350 us; speedup vs baseline: 9.0518x; 1.0768x over previous
//
#include <hip/hip_runtime.h>
#include <hip/hip_bf16.h>

#define NN 40000      // nodes
#define NE 150000     // edges per type
#define HF 512        // H*D
#define NHEAD 4

typedef __bf16 bf16x8 __attribute__((ext_vector_type(8)));
typedef float floatx4 __attribute__((ext_vector_type(4)));
typedef __hip_bfloat16 bf16;
typedef unsigned short u16;

__device__ __forceinline__ float bf2f(bf16 v) { return __bfloat162float(v); }
__device__ __forceinline__ float u2f(u16 v) { return __uint_as_float(((unsigned)v) << 16); }

// async global->LDS DMA, 16B per lane. ldsbase must be wave-uniform;
// HW writes lane i's 16B at ldsbase + i*16 (linear, no per-lane scatter).
__device__ __forceinline__ void gload16(const void* g, void* l) {
    __builtin_amdgcn_global_load_lds(
        (const __attribute__((address_space(1))) void*)g,
        (__attribute__((address_space(3))) void*)l, 16, 0, 0);
}

// explicit drain of outstanding global_load_lds before a barrier.
// __syncthreads alone does NOT order the intrinsic's async LDS write
// (workgroup fence only waits lgkmcnt) -> race without this (round-4 lesson).
__device__ __forceinline__ void wait_vm0() {
    asm volatile("s_waitcnt vmcnt(0)" ::: "memory");
}

__device__ __forceinline__ void store_c(float* p, float v) { *p = v; }
__device__ __forceinline__ void store_c(bf16* p, float v) { *p = __float2bfloat16(v); }

// ---------------- cast fp32 -> bf16, elementwise (8/thread, 16B stores) -----
__global__ void cast_k(const float* __restrict__ in, bf16* __restrict__ out, int n) {
    int i = (blockIdx.x * blockDim.x + threadIdx.x) * 8;
    if (i + 7 < n) {
        float4 v0 = *(const float4*)(in + i);
        float4 v1 = *(const float4*)(in + i + 4);
        union { uint4 u; u16 s[8]; } w;
        float fv[8] = {v0.x, v0.y, v0.z, v0.w, v1.x, v1.y, v1.z, v1.w};
#pragma unroll
        for (int j = 0; j < 8; j++) {
            bf16 b = __float2bfloat16(fv[j]);
            w.s[j] = *(const u16*)&b;
        }
        *(uint4*)(out + i) = w.u;
    } else {
        for (int j = i; j < n; j++) out[j] = __float2bfloat16(in[j]);
    }
}

// ---------------- transpose+cast: WT[n*K+k] = bf16(W[k*N+n]) ----------------
__global__ void transpose_k(const float* __restrict__ W, bf16* __restrict__ WT,
                            int K, int Nn) {
    __shared__ float tile[32][33];
    int n0 = blockIdx.x * 32, k0 = blockIdx.y * 32;
    int tx = threadIdx.x, ty = threadIdx.y;
    int n = n0 + tx, k = k0 + ty;
    if (n < Nn && k < K) tile[ty][tx] = W[(size_t)k * Nn + n];
    __syncthreads();
    int nn = n0 + ty, kk = k0 + tx;
    if (nn < Nn && kk < K) WT[(size_t)nn * K + kk] = __float2bfloat16(tile[tx][ty]);
}

// ---------------- GEMM: C[M,Nn] = A[M,K] * BT[Nn,K]^T ----------------
// 128x128 tile, BK=32, 4 waves (2x2), each wave 64x64 = 4x4 frags 16x16x32.
// Staging: global_load_lds width=16 into LINEAR double-buffered [128][32] LDS.
// Bank-conflict-free via source-side XOR swizzle: LDS slot (row, c) holds
// global 16B-chunk (c ^ ((row>>1)&3)); reads apply the same XOR -> 2-way max.
// 2-phase pipeline: next tile's loads issue before current tile's MFMAs;
// explicit s_waitcnt vmcnt(0) before the barrier drains them (T3 recipe).
// grid: (ntiles, mtiles) — blockIdx.x walks N so consecutive blocks share the
// A row-panel; bijective XCD swizzle keeps panel-sharers on one XCD L2.
template <typename TOUT, bool HAS_BIAS>
__global__ __launch_bounds__(256) void gemm_k(const bf16* __restrict__ A,
                                              const bf16* __restrict__ BT,
                                              TOUT* __restrict__ C,
                                              const float* __restrict__ bias,
                                              int M, int Nn, int K) {
    __shared__ __align__(16) unsigned short As[2][128][32];
    __shared__ __align__(16) unsigned short Bs[2][128][32];

    // bijective XCD swizzle (m204 form; handles nwg % 8 != 0)
    const int nwg = gridDim.x * gridDim.y;
    const int orig = blockIdx.y * gridDim.x + blockIdx.x;
    const int qq = nwg >> 3, r8 = nwg & 7;
    const int xcd = orig & 7, loc = orig >> 3;
    const int swz = (xcd < r8 ? xcd * (qq + 1) : r8 * (qq + 1) + (xcd - r8) * qq) + loc;
    const int ntile = swz % gridDim.x;
    const int mtile = swz / gridDim.x;
    const int m0 = mtile * 128;
    const int n0 = ntile * 128;

    const int t = threadIdx.x;
    const int lane = t & 63;
    const int wave = t >> 6;
    const int wm = wave >> 1, wn = wave & 1;
    const int q = lane >> 4, r = lane & 15;

    // staging geometry: wave w stages rows [w*32, w*32+32) in 2 rounds of 16
    // rows (64 lanes x 16B = 1KB linear). Lane l -> slot row w*32+(l>>2)
    // (+16 round 1), slot chunk l&3. Source chunk = (l&3) ^ ((srow>>1)&3).
    const int srow = wave * 32 + (lane >> 2);
    const int scol = ((lane & 3) ^ ((srow >> 1) & 3)) * 8;  // element offset
    int ar0 = m0 + srow;        if (ar0 >= M)  ar0 = M - 1;
    int ar1 = m0 + srow + 16;   if (ar1 >= M)  ar1 = M - 1;
    int br0 = n0 + srow;        if (br0 >= Nn) br0 = Nn - 1;
    int br1 = n0 + srow + 16;   if (br1 >= Nn) br1 = Nn - 1;
    const unsigned short* Ag0 = (const unsigned short*)A + (size_t)ar0 * K + scol;
    const unsigned short* Ag1 = (const unsigned short*)A + (size_t)ar1 * K + scol;
    const unsigned short* Bg0 = (const unsigned short*)BT + (size_t)br0 * K + scol;
    const unsigned short* Bg1 = (const unsigned short*)BT + (size_t)br1 * K + scol;
    // wave-uniform LDS bases (shorts): wave*1024 within each buffer
    unsigned short* Alb[2] = {&As[0][0][0] + wave * 1024, &As[1][0][0] + wave * 1024};
    unsigned short* Blb[2] = {&Bs[0][0][0] + wave * 1024, &Bs[1][0][0] + wave * 1024};

    // fragment-read chunk offsets (elements), same XOR as staging
    const int rchunk = (q ^ ((r >> 1) & 3)) * 8;

    floatx4 acc[4][4] = {};
    const int nt = K >> 5;
    int cur = 0;
    // prologue: stage tile 0
    gload16(Ag0, Alb[0]);
    gload16(Ag1, Alb[0] + 512);
    gload16(Bg0, Blb[0]);
    gload16(Bg1, Blb[0] + 512);
    wait_vm0();
    __syncthreads();
    for (int tt = 0; tt < nt; tt++) {
        if (tt + 1 < nt) {
            const int k1 = (tt + 1) << 5;
            gload16(Ag0 + k1, Alb[cur ^ 1]);
            gload16(Ag1 + k1, Alb[cur ^ 1] + 512);
            gload16(Bg0 + k1, Blb[cur ^ 1]);
            gload16(Bg1 + k1, Blb[cur ^ 1] + 512);
        }
        bf16x8 a[4], b[4];
#pragma unroll
        for (int i = 0; i < 4; i++)
            a[i] = *(const bf16x8*)&As[cur][wm * 64 + i * 16 + r][rchunk];
#pragma unroll
        for (int j = 0; j < 4; j++)
            b[j] = *(const bf16x8*)&Bs[cur][wn * 64 + j * 16 + r][rchunk];
#pragma unroll
        for (int i = 0; i < 4; i++)
#pragma unroll
            for (int j = 0; j < 4; j++)
                acc[i][j] = __builtin_amdgcn_mfma_f32_16x16x32_bf16(a[i], b[j], acc[i][j], 0, 0, 0);
        wait_vm0();        // prefetched tile fully landed in LDS
        __syncthreads();   // now safe for all waves to swap buffers
        cur ^= 1;
    }

    // hoisted bias (4 columns per thread)
    float bv4[4] = {0.f, 0.f, 0.f, 0.f};
    if (HAS_BIAS) {
#pragma unroll
        for (int j = 0; j < 4; j++) {
            int col = n0 + wn * 64 + j * 16 + r;
            if (col < Nn) bv4[j] = bias[col];
        }
    }
#pragma unroll
    for (int i = 0; i < 4; i++)
#pragma unroll
        for (int j = 0; j < 4; j++)
#pragma unroll
            for (int rr = 0; rr < 4; rr++) {
                int row = m0 + wm * 64 + i * 16 + q * 4 + rr;
                int col = n0 + wn * 64 + j * 16 + r;
                if (row < M && col < Nn) {
                    float v = acc[i][j][rr];
                    if (HAS_BIAS) v += bv4[j];
                    store_c(&C[(size_t)row * Nn + col], v);
                }
            }
}

// ---------------- attention logits, both types fused ------------------------
// featb: [NN][1024] bf16 (cols [0,512)=type0, [512,1024)=type1).
// One wave per node; lane covers 16 elems: type=lane>>5, head=(lane>>3)&3,
// ld=lane&7. el/er layout: [2][NN][NHEAD] fp32.
__global__ void attn_k(const bf16* __restrict__ featb, const float* __restrict__ al_l,
                       const float* __restrict__ ar_l, float* __restrict__ el,
                       float* __restrict__ er) {
    int lane = threadIdx.x & 63;
    int wave = threadIdx.x >> 6;
    int node = blockIdx.x * 4 + wave;
    if (node >= NN) return;
    int tt = lane >> 5, h = (lane >> 3) & 3, ld = lane & 7;
    const u16* fp = (const u16*)featb + (size_t)node * 1024 + lane * 16;
    union { uint4 v; u16 s[8]; } u0, u1;
    u0.v = *(const uint4*)fp;
    u1.v = *(const uint4*)(fp + 8);
    const float* alp = al_l + tt * HF + h * 128 + ld * 16;
    const float* arp = ar_l + tt * HF + h * 128 + ld * 16;
    float sl = 0.f, sr = 0.f;
#pragma unroll
    for (int j = 0; j < 8; j++) {
        float f = u2f(u0.s[j]);
        sl += f * alp[j];
        sr += f * arp[j];
    }
#pragma unroll
    for (int j = 0; j < 8; j++) {
        float f = u2f(u1.s[j]);
        sl += f * alp[8 + j];
        sr += f * arp[8 + j];
    }
#pragma unroll
    for (int off = 4; off >= 1; off >>= 1) {
        sl += __shfl_down(sl, off, 8);
        sr += __shfl_down(sr, off, 8);
    }
    if (ld == 0) {
        size_t o = (size_t)tt * NN * NHEAD + node * NHEAD + h;
        el[o] = sl;
        er[o] = sr;
    }
}

// ---------------- CSR build: degree histogram ----------------
__global__ void deg_count_k(const int* __restrict__ dst, int* __restrict__ deg) {
    int e = blockIdx.x * blockDim.x + threadIdx.x;
    if (e < NE) atomicAdd(&deg[dst[e]], 1);
}

// ---------------- CSR build: exclusive scan (single block, 1024 thr) --------
__global__ void scan_k(const int* __restrict__ deg, int* __restrict__ off) {
    __shared__ int part[1024];
    const int CH = (NN + 1023) >> 10;  // elements per thread
    int t = threadIdx.x;
    int base = t * CH;
    int s = 0;
    for (int i = 0; i < CH; i++) {
        int idx = base + i;
        if (idx < NN) s += deg[idx];
    }
    part[t] = s;
    __syncthreads();
    for (int d = 1; d < 1024; d <<= 1) {
        int v = (t >= d) ? part[t - d] : 0;
        __syncthreads();
        part[t] += v;
        __syncthreads();
    }
    int run = (t == 0) ? 0 : part[t - 1];
    for (int i = 0; i < CH; i++) {
        int idx = base + i;
        if (idx < NN) {
            off[idx] = run;
            run += deg[idx];
        } else if (idx == NN) {
            off[NN] = run;
        }
    }
}

// ---------------- CSR build: fill sorted src list ----------------
__global__ void fill_k(const int* __restrict__ src, const int* __restrict__ dst,
                       const int* __restrict__ off, int* __restrict__ cur,
                       int* __restrict__ csrc) {
    int e = blockIdx.x * blockDim.x + threadIdx.x;
    if (e >= NE) return;
    int d = dst[e];
    int p = atomicAdd(&cur[d], 1);
    csrc[off[d] + p] = src[e];
}

// ---------------- fused gather, both types: softmax + aggregate + bias + act
// One wave per dst node; lane owns 8 contiguous elems of the 512-row (h=lane>>4).
// For each type: online max/exp-sum over CSR, then weighted bf16 gather;
// per-type bias+activation applied, summed across types, single bf16 write.
__global__ __launch_bounds__(256) void gather_k(
    const int* __restrict__ off0, const int* __restrict__ csrc0,
    const int* __restrict__ off1, const int* __restrict__ csrc1,
    const float* __restrict__ el, const float* __restrict__ er,
    const bf16* __restrict__ featb, const float* __restrict__ bb_l,
    bf16* __restrict__ hout, int act) {
    int lane = threadIdx.x & 63;
    int wave = threadIdx.x >> 6;
    int d = blockIdx.x * 4 + wave;
    if (d >= NN) return;
    int h = lane >> 4;
    const int* offs[2] = {off0, off1};
    const int* csrcs[2] = {csrc0, csrc1};

    float out[8] = {};
#pragma unroll
    for (int tt = 0; tt < 2; tt++) {
        const int* off = offs[tt];
        const int* csrc = csrcs[tt];
        const float* elt = el + (size_t)tt * NN * NHEAD;
        int o0 = off[d], o1 = off[d + 1];
        float erd = er[(size_t)tt * NN * NHEAD + d * NHEAD + h];
        // online segment max + exp-sum
        float m = -3.0e38f, sum = 0.f;
        for (int i = o0; i < o1; i++) {
            int s = csrc[i];
            float lg = elt[s * NHEAD + h] + erd;
            lg = lg > 0.f ? lg : 0.2f * lg;
            float mn = fmaxf(m, lg);
            sum = sum * __expf(m - mn) + __expf(lg - mn);
            m = mn;
        }
        float inv = sum > 0.f ? 1.f / sum : 0.f;
        // weighted gather (bf16 feat rows)
        float acc[8] = {};
        for (int i = o0; i < o1; i++) {
            int s = csrc[i];
            float lg = elt[s * NHEAD + h] + erd;
            lg = lg > 0.f ? lg : 0.2f * lg;
            float a = __expf(lg - m) * inv;
            const u16* fp = (const u16*)featb + (size_t)s * 1024 + tt * HF + lane * 8;
            union { uint4 v; u16 s8[8]; } u;
            u.v = *(const uint4*)fp;
#pragma unroll
            for (int j = 0; j < 8; j++) acc[j] += u2f(u.s8[j]) * a;
        }
        // per-type bias + activation, accumulate across types
        const float* bp = bb_l + tt * HF + lane * 8;
        float4 b0 = *(const float4*)bp;
        float4 b1 = *(const float4*)(bp + 4);
        float bv[8] = {b0.x, b0.y, b0.z, b0.w, b1.x, b1.y, b1.z, b1.w};
#pragma unroll
        for (int j = 0; j < 8; j++) {
            float v = acc[j] + bv[j];
            if (act) v = v > 0.f ? v : 0.01f * v;
            out[j] += v;
        }
    }
    union { uint4 v; u16 s[8]; } outw;
#pragma unroll
    for (int j = 0; j < 8; j++) {
        bf16 ob = __float2bfloat16(out[j]);
        outw.s[j] = *(const u16*)&ob;
    }
    *(uint4*)((u16*)hout + (size_t)d * HF + lane * 8) = outw.v;
}

extern "C" void kernel_launch(void* const* d_in, const int* in_sizes, int n_in,
                              void* d_out, int out_size, void* d_ws, size_t ws_size,
                              hipStream_t stream) {
    const float* x = (const float*)d_in[0];
    const int* srcs[2] = {(const int*)d_in[1], (const int*)d_in[3]};
    const int* dsts[2] = {(const int*)d_in[2], (const int*)d_in[4]};
    const float* W[3] = {(const float*)d_in[5], (const float*)d_in[9], (const float*)d_in[13]};
    const float* al[3] = {(const float*)d_in[6], (const float*)d_in[10], (const float*)d_in[14]};
    const float* ar[3] = {(const float*)d_in[7], (const float*)d_in[11], (const float*)d_in[15]};
    const float* bb[3] = {(const float*)d_in[8], (const float*)d_in[12], (const float*)d_in[16]};
    const float* Wout = (const float*)d_in[17];
    const float* bout = (const float*)d_in[18];

    // workspace layout (~95 MB)
    char* ws = (char*)d_ws;
    size_t off = 0;
    auto walloc = [&](size_t bytes) {
        void* p = ws + off;
        off = (off + bytes + 255) & ~(size_t)255;
        return p;
    };
    bf16* h0 = (bf16*)walloc((size_t)NN * HF * 2);
    bf16* h1 = (bf16*)walloc((size_t)NN * HF * 2);
    float* el = (float*)walloc((size_t)2 * NN * NHEAD * 4);
    float* er = (float*)walloc((size_t)2 * NN * NHEAD * 4);
    bf16* WT = (bf16*)walloc((size_t)2983 * 512 * 2);
    bf16* WT2 = (bf16*)walloc((size_t)1024 * 1024 * 2);
    int* deg = (int*)walloc((size_t)NN * 4);
    int* cur = (int*)walloc((size_t)NN * 4);
    int* offs[2];
    int* csrc[2];
    for (int t = 0; t < 2; t++) {
        offs[t] = (int*)walloc((size_t)(NN + 1) * 4);
        csrc[t] = (int*)walloc((size_t)NE * 4);
    }

    // dead regions of d_out used as scratch (out is fp32, 477 MB; final GEMM
    // overwrites everything). xb: [81.92, 163.84) MB, featb: [163.84, 245.8) MB
    bf16* xb = (bf16*)((char*)d_out + (size_t)NN * HF * 4);
    bf16* featb = (bf16*)((char*)d_out + (size_t)NN * HF * 4 + (size_t)NN * 1024 * 2);

    // cast x (fp32 -> bf16) once
    cast_k<<<(NN * 1024 / 8 + 255) / 256, 256, 0, stream>>>(x, xb, NN * 1024);

    // build dst-CSR per edge type (reused across all 3 layers)
    const int EB = (NE + 255) / 256;
    for (int t = 0; t < 2; t++) {
        hipMemsetAsync(deg, 0, (size_t)NN * 4, stream);
        hipMemsetAsync(cur, 0, (size_t)NN * 4, stream);
        deg_count_k<<<EB, 256, 0, stream>>>(dsts[t], deg);
        scan_k<<<1, 1024, 0, stream>>>(deg, offs[t]);
        fill_k<<<EB, 256, 0, stream>>>(srcs[t], dsts[t], offs[t], cur, csrc[t]);
    }

    const int MT = (NN + 127) / 128;  // 313 M-tiles

    for (int l = 0; l < 3; l++) {
        const int K = (l == 0) ? 1024 : 512;
        const bf16* hin = (l == 0) ? xb : ((l == 1) ? h0 : h1);
        bf16* hout = (l == 0) ? h0 : ((l == 1) ? h1 : h0);
        const int act = (l < 2) ? 1 : 0;
        // both types' weights -> WT2 [1024][K]
        for (int t = 0; t < 2; t++)
            transpose_k<<<dim3(512 / 32, K / 32), dim3(32, 32), 0, stream>>>(
                W[l] + (size_t)t * K * 512, WT2 + (size_t)t * 512 * K, K, 512);
        // featb[NN][1024] = hin @ [W_t0 | W_t1]   (bf16 out)
        gemm_k<bf16, false><<<dim3(1024 / 128, MT), 256, 0, stream>>>(
            hin, WT2, featb, nullptr, NN, 1024, K);
        // logits for both types
        attn_k<<<NN / 4, 256, 0, stream>>>(featb, al[l], ar[l], el, er);
        // fused both-type edge-softmax + aggregate + bias + act + type-sum
        gather_k<<<NN / 4, 256, 0, stream>>>(offs[0], csrc[0], offs[1], csrc[1],
                                             el, er, featb, bb[l], hout, act);
    }

    // final projection: out = h @ Wout + bout   [40000 x 2983] fp32
    transpose_k<<<dim3((2983 + 31) / 32, 512 / 32), dim3(32, 32), 0, stream>>>(
        Wout, WT, 512, 2983);
    gemm_k<float, true><<<dim3((2983 + 127) / 128, MT), 256, 0, stream>>>(
        h0, WT, (float*)d_out, bout, NN, 2983, 512);
}